// Round 2
// baseline (620.842 us; speedup 1.0000x reference)
//
#include <hip/hip_runtime.h>

// EdgeGCN: 2-layer GCN + edge scorer on MI355X.
// N=100000 nodes, E=3200000 edges, F_IN=128, HID=16, OUT=1.
//
// ws layout (floats):
//   [0, N)        deg (as uint counts) -> dinv (in-place)
//   [N, 17N)      S   : s1 = (x@W1)*dinv, then s2 = (h1@W2)*dinv (in-place per row)
//   [17N, 33N)    ACC : scatter accumulator (zeroed before each layer)
//   [33N, 35N)    UV  : per-node (u,v) = (h2 . Wfc[0:16], h2 . Wfc[16:32])
// total 35N floats = 14 MB.

constexpr int NN = 100000;
constexpr int NE = 3200000;
constexpr int FI = 128;
constexpr int HD = 16;

__global__ __launch_bounds__(256) void k_deg(const int* __restrict__ dst,
                                             unsigned* __restrict__ deg) {
    int t = blockIdx.x * 256 + threadIdx.x;            // NE/4 threads
    int4 d4 = reinterpret_cast<const int4*>(dst)[t];
    atomicAdd(&deg[d4.x], 1u);
    atomicAdd(&deg[d4.y], 1u);
    atomicAdd(&deg[d4.z], 1u);
    atomicAdd(&deg[d4.w], 1u);
}

__global__ __launch_bounds__(256) void k_dinv(float* __restrict__ buf) {
    int i = blockIdx.x * 256 + threadIdx.x;
    if (i < NN) {
        unsigned d = reinterpret_cast<const unsigned*>(buf)[i];
        buf[i] = 1.0f / sqrtf((float)d + 1.0f);        // deg includes self-loop (+1)
    }
}

// S = (x @ W1) * dinv   -- one thread per node, W1 read thread-uniformly (SGPR loads)
__global__ __launch_bounds__(256) void k_xw1(const float* __restrict__ x,
                                             const float* __restrict__ W1,
                                             const float* __restrict__ dinv,
                                             float* __restrict__ S) {
    int i = blockIdx.x * 256 + threadIdx.x;
    if (i >= NN) return;
    const float4* xr = reinterpret_cast<const float4*>(x + (size_t)i * FI);
    float acc[HD];
    #pragma unroll
    for (int k = 0; k < HD; ++k) acc[k] = 0.f;
    #pragma unroll 8
    for (int jc = 0; jc < FI / 4; ++jc) {
        float4 xv = xr[jc];
        const float* w = W1 + jc * 4 * HD;
        #pragma unroll
        for (int k = 0; k < HD; ++k)
            acc[k] += xv.x * w[k] + xv.y * w[HD + k] + xv.z * w[2 * HD + k] + xv.w * w[3 * HD + k];
    }
    float dv = dinv[i];
    float4* out = reinterpret_cast<float4*>(S + (size_t)i * HD);
    #pragma unroll
    for (int q = 0; q < 4; ++q)
        out[q] = make_float4(acc[q * 4 + 0] * dv, acc[q * 4 + 1] * dv,
                             acc[q * 4 + 2] * dv, acc[q * 4 + 3] * dv);
}

// ACC[dst] += S[src]  (norm factors folded into S and the epilogue)
__global__ __launch_bounds__(256) void k_scatter(const int* __restrict__ src,
                                                 const int* __restrict__ dst,
                                                 const float* __restrict__ S,
                                                 float* __restrict__ ACC) {
    int t = blockIdx.x * 256 + threadIdx.x;            // NE*16 threads
    int e = t >> 4;
    int k = t & 15;
    int s = src[e];
    int d = dst[e];
    unsafeAtomicAdd(&ACC[(size_t)d * HD + k], S[(size_t)s * HD + k]);
}

// h1 = relu(dinv*(ACC + S) + b1)  (registers only), then S <- (h1 @ W2) * dinv
__global__ __launch_bounds__(256) void k_h1s2(const float* __restrict__ ACC,
                                              float* __restrict__ S,
                                              const float* __restrict__ dinv,
                                              const float* __restrict__ b1,
                                              const float* __restrict__ W2) {
    int i = blockIdx.x * 256 + threadIdx.x;
    if (i >= NN) return;
    float dv = dinv[i];
    const float4* ar = reinterpret_cast<const float4*>(ACC + (size_t)i * HD);
    float4* sr = reinterpret_cast<float4*>(S + (size_t)i * HD);
    float h[HD];
    #pragma unroll
    for (int q = 0; q < 4; ++q) {
        float4 a = ar[q];
        float4 s = sr[q];
        h[q * 4 + 0] = fmaxf(dv * (a.x + s.x) + b1[q * 4 + 0], 0.f);
        h[q * 4 + 1] = fmaxf(dv * (a.y + s.y) + b1[q * 4 + 1], 0.f);
        h[q * 4 + 2] = fmaxf(dv * (a.z + s.z) + b1[q * 4 + 2], 0.f);
        h[q * 4 + 3] = fmaxf(dv * (a.w + s.w) + b1[q * 4 + 3], 0.f);
    }
    float acc[HD];
    #pragma unroll
    for (int k = 0; k < HD; ++k) acc[k] = 0.f;
    #pragma unroll
    for (int j = 0; j < HD; ++j) {
        float hj = h[j];
        #pragma unroll
        for (int k = 0; k < HD; ++k) acc[k] += hj * W2[j * HD + k];
    }
    #pragma unroll
    for (int q = 0; q < 4; ++q)
        sr[q] = make_float4(acc[q * 4 + 0] * dv, acc[q * 4 + 1] * dv,
                            acc[q * 4 + 2] * dv, acc[q * 4 + 3] * dv);
}

// h2 = dinv*(ACC + S) + b2 (no relu); UV[i] = (h2 . Wfc[0:16], h2 . Wfc[16:32])
__global__ __launch_bounds__(256) void k_uv(const float* __restrict__ ACC,
                                            const float* __restrict__ S,
                                            const float* __restrict__ dinv,
                                            const float* __restrict__ b2,
                                            const float* __restrict__ Wfc,
                                            float2* __restrict__ UV) {
    int i = blockIdx.x * 256 + threadIdx.x;
    if (i >= NN) return;
    float dv = dinv[i];
    const float4* ar = reinterpret_cast<const float4*>(ACC + (size_t)i * HD);
    const float4* sr = reinterpret_cast<const float4*>(S + (size_t)i * HD);
    float u = 0.f, v = 0.f;
    #pragma unroll
    for (int q = 0; q < 4; ++q) {
        float4 a = ar[q];
        float4 s = sr[q];
        float h0 = dv * (a.x + s.x) + b2[q * 4 + 0];
        float h1 = dv * (a.y + s.y) + b2[q * 4 + 1];
        float h2 = dv * (a.z + s.z) + b2[q * 4 + 2];
        float h3 = dv * (a.w + s.w) + b2[q * 4 + 3];
        u += h0 * Wfc[q * 4 + 0] + h1 * Wfc[q * 4 + 1] + h2 * Wfc[q * 4 + 2] + h3 * Wfc[q * 4 + 3];
        v += h0 * Wfc[HD + q * 4 + 0] + h1 * Wfc[HD + q * 4 + 1] + h2 * Wfc[HD + q * 4 + 2] + h3 * Wfc[HD + q * 4 + 3];
    }
    UV[i] = make_float2(u, v);
}

__global__ __launch_bounds__(256) void k_pred(const int* __restrict__ src,
                                              const int* __restrict__ dst,
                                              const float2* __restrict__ UV,
                                              const float* __restrict__ bfc,
                                              float* __restrict__ out) {
    int t = blockIdx.x * 256 + threadIdx.x;            // NE/4 threads
    int4 s4 = reinterpret_cast<const int4*>(src)[t];
    int4 d4 = reinterpret_cast<const int4*>(dst)[t];
    float bb = bfc[0];
    float4 o;
    o.x = UV[s4.x].x + UV[d4.x].y + bb;
    o.y = UV[s4.y].x + UV[d4.y].y + bb;
    o.z = UV[s4.z].x + UV[d4.z].y + bb;
    o.w = UV[s4.w].x + UV[d4.w].y + bb;
    reinterpret_cast<float4*>(out)[t] = o;
}

extern "C" void kernel_launch(void* const* d_in, const int* in_sizes, int n_in,
                              void* d_out, int out_size, void* d_ws, size_t ws_size,
                              hipStream_t stream) {
    const float* x   = (const float*)d_in[0];
    const int*   ei  = (const int*)d_in[1];
    const float* W1  = (const float*)d_in[2];
    const float* b1  = (const float*)d_in[3];
    const float* W2  = (const float*)d_in[4];
    const float* b2  = (const float*)d_in[5];
    const float* Wfc = (const float*)d_in[6];
    const float* bfc = (const float*)d_in[7];
    const int* src = ei;            // edge_index[0]
    const int* dst = ei + NE;       // edge_index[1]

    float* ws   = (float*)d_ws;
    float* dinv = ws;                          // N floats (deg counts first)
    float* S    = ws + NN;                     // 16N
    float* ACC  = ws + NN + 16 * (size_t)NN;   // 16N
    float2* UV  = (float2*)(ws + NN + 32 * (size_t)NN); // 2N
    float* out  = (float*)d_out;

    hipMemsetAsync(dinv, 0, NN * sizeof(float), stream);
    hipMemsetAsync(ACC, 0, (size_t)16 * NN * sizeof(float), stream);

    k_deg<<<NE / 4 / 256, 256, 0, stream>>>(dst, (unsigned*)dinv);
    k_dinv<<<(NN + 255) / 256, 256, 0, stream>>>(dinv);
    k_xw1<<<(NN + 255) / 256, 256, 0, stream>>>(x, W1, dinv, S);
    k_scatter<<<NE * 16 / 256, 256, 0, stream>>>(src, dst, S, ACC);
    k_h1s2<<<(NN + 255) / 256, 256, 0, stream>>>(ACC, S, dinv, b1, W2);
    hipMemsetAsync(ACC, 0, (size_t)16 * NN * sizeof(float), stream);
    k_scatter<<<NE * 16 / 256, 256, 0, stream>>>(src, dst, S, ACC);
    k_uv<<<(NN + 255) / 256, 256, 0, stream>>>(ACC, S, dinv, b2, Wfc, UV);
    k_pred<<<NE / 4 / 256, 256, 0, stream>>>(src, dst, UV, bfc, out);
}